// Round 13
// baseline (32.189 us; speedup 1.0000x reference)
//
#include <hip/hip_runtime.h>

// Post_process_deconv: out = depth + b + sum_k w[k] * (weight[k] - mean_k(weight)) *
//                           bilinear(depth, y - 1 + kh + dy_k, x - 1 + kw + dx_k)
// Shapes: depth [B,1,H,W], weight [B,9,H,W], offset [B,18,H,W], w [1,1,3,3], b [1]
// B=2, H=352, W=1216, K=3, pad=1. All fp32.
//
// Round 13: streaming BW is capped by outstanding-request count x request size
// (dword streams plateau ~2.4 TB/s; float4 streams reach ~6.3 TB/s, m13).
// So the 27 weight/offset planes are staged per-block via COOPERATIVE
// dwordx4 loads (27 planes x 4 rows x 64 px = 27KB/block, 8 float4 loads per
// thread instead of 27 dword loads) into LDS; each thread then reads its 27
// private values from LDS (stride-1 across lanes, conflict-free). Depth tile
// (64x4 + halo7, zero-filled OOB) also in LDS as before. Branchless tap loop
// + rare exact out-of-halo fixup (per-k data re-read from LDS, no scratch).

#define KK 3
#define K2 9
#define PAD 1
#define BB 2
#define HH 352
#define WW 1216

#define TX 64                       // tile width  (19 tiles)
#define TY 4                        // tile height (88 tiles)
#define NTX (WW / TX)               // 19
#define NTY (HH / TY)               // 88
#define TILES (NTY * NTX)           // 1672
#define NBLK (BB * TILES)           // 3344
#define HALO 7
#define SROWS (TY + 2 * HALO + 1)   // 19
#define SCOLS (TX + 2 * HALO + 2)   // 80
#define SN (SROWS * SCOLS)          // 1520
#define NSTG ((SN + 255) / 256)     // 6

#define CPP (TX / 4)                // 16 float4 chunks per row segment
#define NWCH (K2 * TY * CPP)        // 576  weight chunks (9 KB)
#define NOCH (2 * K2 * TY * CPP)    // 1152 offset chunks (18 KB)

__global__ __launch_bounds__(256, 4) void ppd_kernel(
    const float* __restrict__ depth,   // [B, H*W]
    const float* __restrict__ weight,  // [B, 9, H*W]
    const float* __restrict__ offset,  // [B, 18, H*W]
    const float* __restrict__ wk,      // [9]
    const float* __restrict__ bias,    // [1]
    float* __restrict__ out)           // [B, H*W]
{
    constexpr int HW = HH * WW;

    __shared__ float sw[K2 * 256];       //  9216 B  [k][pixel-in-tile]
    __shared__ float so[2 * K2 * 256];   // 18432 B  [c][pixel-in-tile]
    __shared__ float sdep[SN];           //  6080 B  depth tile + halo

    const int bid  = blockIdx.x;
    const int b    = bid / TILES;
    const int trem = bid - b * TILES;
    const int ty   = trem / NTX;
    const int tx   = trem - ty * NTX;

    const int tid = threadIdx.x;
    const int lx  = tid & (TX - 1);
    const int lyq = tid >> 6;            // 0..3
    const int x   = tx * TX + lx;
    const int y   = ty * TY + lyq;

    const int base_y = ty * TY - HALO;
    const int base_x = tx * TX - HALO;

    const float* dimg  = depth  + (size_t)b * HW;
    const float* wbase = weight + (size_t)b * (K2 * HW);
    const float* obase = offset + (size_t)b * (2 * K2 * HW);

    // ---- Phase A: issue ALL global loads (wide, cooperative) ----
    // weight: 576 float4 chunks -> 3 iterations (last: tid<64)
    float4 wreg[3];
    int    wdst[3];
#pragma unroll
    for (int i = 0; i < 3; ++i) {
        const int c  = tid + i * 256;
        const bool ok = (c < NWCH);
        const int cc = ok ? c : 0;
        const int k   = cc >> 6;          // plane 0..8
        const int rem = cc & 63;
        const int r   = rem >> 4;         // row 0..3
        const int c16 = rem & 15;         // chunk in row
        const float* src = wbase + (size_t)k * HW + (ty * TY + r) * WW + tx * TX + c16 * 4;
        wreg[i] = *reinterpret_cast<const float4*>(src);
        wdst[i] = ok ? (k * 256 + r * 64 + c16 * 4) : -1;
    }
    // offset: 1152 float4 chunks -> 5 iterations (last: tid<128)
    float4 oreg[5];
    int    odst[5];
#pragma unroll
    for (int i = 0; i < 5; ++i) {
        const int c  = tid + i * 256;
        const bool ok = (c < NOCH);
        const int cc = ok ? c : 0;
        const int p   = cc >> 6;          // plane 0..17
        const int rem = cc & 63;
        const int r   = rem >> 4;
        const int c16 = rem & 15;
        const float* src = obase + (size_t)p * HW + (ty * TY + r) * WW + tx * TX + c16 * 4;
        oreg[i] = *reinterpret_cast<const float4*>(src);
        odst[i] = ok ? (p * 256 + r * 64 + c16 * 4) : -1;
    }
    // depth tile (zero-filled OOB): 6 scalar loads
    float dstg[NSTG];
#pragma unroll
    for (int i = 0; i < NSTG; ++i) {
        const int t = tid + i * 256;
        const int r = t / SCOLS;
        const int c = t - r * SCOLS;
        const int gy = base_y + r;
        const int gx = base_x + c;
        float v = 0.f;
        if (t < SN && (unsigned)gy < (unsigned)HH && (unsigned)gx < (unsigned)WW)
            v = dimg[gy * WW + gx];
        dstg[i] = v;
    }

    // ---- Phase B: LDS writes, one barrier ----
#pragma unroll
    for (int i = 0; i < 3; ++i)
        if (wdst[i] >= 0) *reinterpret_cast<float4*>(&sw[wdst[i]]) = wreg[i];
#pragma unroll
    for (int i = 0; i < 5; ++i)
        if (odst[i] >= 0) *reinterpret_cast<float4*>(&so[odst[i]]) = oreg[i];
#pragma unroll
    for (int i = 0; i < NSTG; ++i) {
        const int t = tid + i * 256;
        if (t < SN) sdep[t] = dstg[i];
    }
    __syncthreads();

    // ---- per-thread private values off the LDS pipe (stride-1, no conflict) ----
    float wv[K2], dyv[K2], dxv[K2];
#pragma unroll
    for (int k = 0; k < K2; ++k) {
        wv[k]  = sw[k * 256 + tid];
        dyv[k] = so[(2 * k) * 256 + tid];
        dxv[k] = so[(2 * k + 1) * 256 + tid];
    }

    float wsum = 0.f;
#pragma unroll
    for (int k = 0; k < K2; ++k) wsum += wv[k];
    const float wmean = wsum * (1.0f / 9.0f);

    // ---- branchless tap loop (clamped LDS reads) + miss bits ----
    float acc = 0.f;
    unsigned miss = 0u;
#pragma unroll
    for (int k = 0; k < K2; ++k) {
        const int kh = k / KK;
        const int kw = k - kh * KK;
        const float py = (float)(y - PAD + kh) + dyv[k];
        const float px = (float)(x - PAD + kw) + dxv[k];
        const float y0f = floorf(py);
        const float x0f = floorf(px);
        const float fy = py - y0f;
        const float fx = px - x0f;
        const int y0 = (int)y0f;
        const int x0 = (int)x0f;

        const int lr = y0 - base_y;
        const int lc = x0 - base_x;
        const int lrc = min(max(lr, 0), SROWS - 2);
        const int lcc = min(max(lc, 0), SCOLS - 2);
        const bool ok = ((unsigned)lr <= (unsigned)(SROWS - 2)) &
                        ((unsigned)lc <= (unsigned)(SCOLS - 2));

        const float* r0 = &sdep[lrc * SCOLS + lcc];
        const float v00 = r0[0];
        const float v01 = r0[1];
        const float v10 = r0[SCOLS];
        const float v11 = r0[SCOLS + 1];
        const float smp = (1.f - fy) * ((1.f - fx) * v00 + fx * v01)
                        + fy         * ((1.f - fx) * v10 + fx * v11);

        miss |= ok ? 0u : (1u << k);
        acc = fmaf(wk[k] * (wv[k] - wmean), smp, acc);
    }

    // ---- rare exact fixup (per-k data re-read from LDS; runtime LDS
    //      indexing is scratch-safe) ----
    if (miss) {
#pragma unroll 1
        for (int k = 0; k < K2; ++k) {
            if (!(miss & (1u << k))) continue;
            const int kh = k / KK;
            const int kw = k - kh * KK;
            const float dy  = so[(2 * k) * 256 + tid];
            const float dx  = so[(2 * k + 1) * 256 + tid];
            const float wvk = sw[k * 256 + tid];
            const float py = (float)(y - PAD + kh) + dy;
            const float px = (float)(x - PAD + kw) + dx;
            const float y0f = floorf(py);
            const float x0f = floorf(px);
            const float fy = py - y0f;
            const float fx = px - x0f;
            const int y0 = (int)y0f;
            const int x0 = (int)x0f;

            // recompute the (wrong) fast-path sample exactly as above
            const int lrc = min(max(y0 - base_y, 0), SROWS - 2);
            const int lcc = min(max(x0 - base_x, 0), SCOLS - 2);
            const float* r0 = &sdep[lrc * SCOLS + lcc];
            const float sf = (1.f - fy) * ((1.f - fx) * r0[0] + fx * r0[1])
                           + fy         * ((1.f - fx) * r0[SCOLS] + fx * r0[SCOLS + 1]);

            // true sample via global clamped loads + validity-folded weights
            const float wy0 = ((unsigned)y0       < (unsigned)HH) ? (1.f - fy) : 0.f;
            const float wy1 = ((unsigned)(y0 + 1) < (unsigned)HH) ? fy         : 0.f;
            const float wx0 = ((unsigned)x0       < (unsigned)WW) ? (1.f - fx) : 0.f;
            const float wx1 = ((unsigned)(x0 + 1) < (unsigned)WW) ? fx         : 0.f;
            const int y0c = min(max(y0, 0), HH - 1);
            const int y1c = min(max(y0 + 1, 0), HH - 1);
            const int x0c = min(max(x0, 0), WW - 1);
            const int x1c = min(max(x0 + 1, 0), WW - 1);
            const float st = wy0 * (wx0 * dimg[y0c * WW + x0c] + wx1 * dimg[y0c * WW + x1c])
                           + wy1 * (wx0 * dimg[y1c * WW + x0c] + wx1 * dimg[y1c * WW + x1c]);

            acc = fmaf(wk[k] * (wvk - wmean), st - sf, acc);
        }
    }

    // residual from LDS; epilogue
    const float dres = sdep[(lyq + HALO) * SCOLS + (lx + HALO)];
    out[(size_t)b * HW + y * WW + x] = acc + bias[0] + dres;
}

extern "C" void kernel_launch(void* const* d_in, const int* in_sizes, int n_in,
                              void* d_out, int out_size, void* d_ws, size_t ws_size,
                              hipStream_t stream) {
    const float* depth  = (const float*)d_in[0];
    const float* weight = (const float*)d_in[1];
    const float* offset = (const float*)d_in[2];
    const float* wk     = (const float*)d_in[3];
    const float* bias   = (const float*)d_in[4];
    float* out = (float*)d_out;

    ppd_kernel<<<NBLK, 256, 0, stream>>>(depth, weight, offset, wk, bias, out);
}

// Round 14
// 27.735 us; speedup vs baseline: 1.1606x; 1.1606x over previous
//
#include <hip/hip_runtime.h>

// Post_process_deconv: out = depth + b + sum_k w[k] * (weight[k] - mean_k(weight)) *
//                           bilinear(depth, y - 1 + kh + dy_k, x - 1 + kw + dx_k)
// Shapes: depth [B,1,H,W], weight [B,9,H,W], offset [B,18,H,W], w [1,1,3,3], b [1]
// B=2, H=352, W=1216, K=3, pad=1. All fp32.
//
// Round 14: no LDS, no barrier, no staging. Depth (3.4MB) is L2-resident;
// XCD-chunked block swizzle (3344 = 8x418, bijective) gives each XCD a ~214KB
// depth band -> gathers are L2/L1 hits. Per thread, four register phases:
//   (1) 28 streaming loads issued (27 planes + residual);
//   (2) all 9 tap addresses + fracs; boundary predicates packed into 6 u32
//       bitmasks (keeps VGPR ~95, under the launch_bounds(256,4) cap of 128);
//   (3) all 18 dwordx2 gathers issued back-to-back (one wait, full MLP);
//   (4) pure-VALU bilinear + accumulate (validity folded into weights).
// Exact fp32 for ALL offsets -- no halo approximation, no fixup path.

#define KK 3
#define K2 9
#define PAD 1
#define BB 2
#define HH 352
#define WW 1216

#define TX 64
#define TY 4
#define NTX (WW / TX)               // 19
#define NTY (HH / TY)               // 88
#define TILES (NTY * NTX)           // 1672
#define NBLK (BB * TILES)           // 3344 = 8 * 418
#define CHUNK (NBLK / 8)            // 418 blocks per XCD chunk

__global__ __launch_bounds__(256, 4) void ppd_kernel(
    const float* __restrict__ depth,   // [B, H*W]
    const float* __restrict__ weight,  // [B, 9, H*W]
    const float* __restrict__ offset,  // [B, 18, H*W]
    const float* __restrict__ wk,      // [9]
    const float* __restrict__ bias,    // [1]
    float* __restrict__ out)           // [B, H*W]
{
    constexpr int HW = HH * WW;

    // XCD-chunked bijective swizzle: default dispatch round-robins blockIdx
    // across the 8 XCDs; remap so XCD n owns a contiguous band of tiles
    // (~214KB of depth -> L2-resident gathers).
    const int bid0 = blockIdx.x;
    const int bid  = (bid0 & 7) * CHUNK + (bid0 >> 3);

    const int b    = bid / TILES;
    const int trem = bid - b * TILES;
    const int ty   = trem / NTX;
    const int tx   = trem - ty * NTX;

    const int tid = threadIdx.x;
    const int lx  = tid & (TX - 1);
    const int lyq = tid >> 6;            // 0..3
    const int x   = tx * TX + lx;
    const int y   = ty * TY + lyq;
    const int hw  = y * WW + x;

    const float* dimg = depth  + (size_t)b * HW;
    const float* wgt  = weight + (size_t)b * (K2 * HW) + hw;
    const float* off  = offset + (size_t)b * (2 * K2 * HW) + hw;

    // ---- Phase 1: all 28 streaming loads issued ----
    float wv[K2], dyv[K2], dxv[K2];
#pragma unroll
    for (int k = 0; k < K2; ++k) {
        dyv[k] = off[(2 * k)     * HW];
        dxv[k] = off[(2 * k + 1) * HW];
    }
#pragma unroll
    for (int k = 0; k < K2; ++k) wv[k] = wgt[k * HW];
    const float dres = dimg[hw];

    // ---- Phase 2: all tap addresses + fracs + packed predicates ----
    float fyv[K2], fxv[K2];
    int   o0[K2], o1[K2];
    unsigned mY0 = 0, mY1 = 0, mX0 = 0, mX1 = 0, mLo0 = 0, mLo1 = 0;
#pragma unroll
    for (int k = 0; k < K2; ++k) {
        const int kh = k / KK;
        const int kw = k - kh * KK;
        const float py = (float)(y - PAD + kh) + dyv[k];
        const float px = (float)(x - PAD + kw) + dxv[k];
        const float y0f = floorf(py);
        const float x0f = floorf(px);
        fyv[k] = py - y0f;
        fxv[k] = px - x0f;
        const int y0 = (int)y0f;
        const int x0 = (int)x0f;

        mY0  |= (unsigned)((unsigned)y0       < (unsigned)HH) << k;
        mY1  |= (unsigned)((unsigned)(y0 + 1) < (unsigned)HH) << k;
        mX0  |= (unsigned)((unsigned)x0       < (unsigned)WW) << k;
        mX1  |= (unsigned)((unsigned)(x0 + 1) < (unsigned)WW) << k;
        mLo0 |= (unsigned)(x0 < WW - 1) << k;
        mLo1 |= (unsigned)(x0 < 0)      << k;

        const int y0c = min(max(y0, 0), HH - 1);
        const int y1c = min(max(y0 + 1, 0), HH - 1);
        const int xb  = min(max(x0, 0), WW - 2);
        o0[k] = y0c * WW + xb;
        o1[k] = y1c * WW + xb;
    }

    // ---- Phase 3: all 18 row-pair gathers issued back-to-back ----
    float2 p0[K2], p1[K2];
#pragma unroll
    for (int k = 0; k < K2; ++k) {
        __builtin_memcpy(&p0[k], dimg + o0[k], 8);
        __builtin_memcpy(&p1[k], dimg + o1[k], 8);
    }

    float wsum = 0.f;
#pragma unroll
    for (int k = 0; k < K2; ++k) wsum += wv[k];
    const float wmean = wsum * (1.0f / 9.0f);

    // ---- Phase 4: pure-VALU bilinear + accumulate ----
    float acc = 0.f;
#pragma unroll
    for (int k = 0; k < K2; ++k) {
        const float fy = fyv[k];
        const float fx = fxv[k];
        const float wy0 = ((mY0 >> k) & 1) ? (1.f - fy) : 0.f;
        const float wy1 = ((mY1 >> k) & 1) ? fy         : 0.f;
        const float wx0 = ((mX0 >> k) & 1) ? (1.f - fx) : 0.f;
        const float wx1 = ((mX1 >> k) & 1) ? fx         : 0.f;
        const bool lo0 = (mLo0 >> k) & 1;
        const bool lo1 = (mLo1 >> k) & 1;

        const float v00 = lo0 ? p0[k].x : p0[k].y;
        const float v01 = lo1 ? p0[k].x : p0[k].y;
        const float v10 = lo0 ? p1[k].x : p1[k].y;
        const float v11 = lo1 ? p1[k].x : p1[k].y;

        const float s = wy0 * (wx0 * v00 + wx1 * v01)
                      + wy1 * (wx0 * v10 + wx1 * v11);
        acc = fmaf(wk[k] * (wv[k] - wmean), s, acc);
    }

    out[(size_t)b * HW + hw] = acc + bias[0] + dres;
}

extern "C" void kernel_launch(void* const* d_in, const int* in_sizes, int n_in,
                              void* d_out, int out_size, void* d_ws, size_t ws_size,
                              hipStream_t stream) {
    const float* depth  = (const float*)d_in[0];
    const float* weight = (const float*)d_in[1];
    const float* offset = (const float*)d_in[2];
    const float* wk     = (const float*)d_in[3];
    const float* bias   = (const float*)d_in[4];
    float* out = (float*)d_out;

    ppd_kernel<<<NBLK, 256, 0, stream>>>(depth, weight, offset, wk, bias, out);
}

// Round 15
// 21.337 us; speedup vs baseline: 1.5086x; 1.2999x over previous
//
#include <hip/hip_runtime.h>

// Post_process_deconv: out = depth + b + sum_k w[k] * (weight[k] - mean_k(weight)) *
//                           bilinear(depth, y - 1 + kh + dy_k, x - 1 + kw + dx_k)
// Shapes: depth [B,1,H,W], weight [B,9,H,W], offset [B,18,H,W], w [1,1,3,3], b [1]
// B=2, H=352, W=1216, K=3, pad=1. All fp32.
//
// Round 15 = round 10 (best, 23.5us: row-pair LDS tile, phase-split batched
// taps, one barrier) + two locality changes proven/targeted by r14:
//  1. bijective XCD-chunked block swizzle (3344 = 8*418): each XCD owns a
//     contiguous tile band -> depth band L2-resident, stream lines shared
//     between consecutive blocks on the same XCD (r14: FETCH 56.5->47 MB).
//  2. nontemporal loads for the single-use weight/offset streams (+ nt store
//     for out): keep them out of L2's LRU so depth/prefetch lines survive.

#define KK 3
#define K2 9
#define PAD 1
#define BB 2
#define HH 352
#define WW 1216

#define TX 64                       // tile width  (19 tiles)
#define TY 4                        // tile height (88 tiles)
#define NTX (WW / TX)
#define NTY (HH / TY)
#define TILES (NTY * NTX)           // 1672
#define NBLK (BB * TILES)           // 3344 = 8 * 418
#define CHUNK (NBLK / 8)            // 418
#define HALO 7
#define SROWS (TY + 2 * HALO + 1)   // 19 raw rows
#define PROWS (SROWS - 1)           // 18 packed row-pair rows
#define SCOLS (TX + 2 * HALO + 2)   // 80
#define PN (PROWS * SCOLS)          // 1440 packed entries
#define NSTG ((PN + 255) / 256)     // 6

__global__ __launch_bounds__(256, 4) void ppd_kernel(
    const float* __restrict__ depth,   // [B, H*W]
    const float* __restrict__ weight,  // [B, 9, H*W]
    const float* __restrict__ offset,  // [B, 18, H*W]
    const float* __restrict__ wk,      // [9]
    const float* __restrict__ bias,    // [1]
    float* __restrict__ out)           // [B, H*W]
{
    constexpr int HW = HH * WW;

    __shared__ float2 pd[PN];           // 11520 B

    // bijective XCD-chunked swizzle (3344 % 8 == 0)
    const int bid0 = blockIdx.x;
    const int bid  = (bid0 & 7) * CHUNK + (bid0 >> 3);

    const int b   = bid / TILES;
    const int rem = bid - b * TILES;
    const int ty  = rem / NTX;
    const int tx  = rem - ty * NTX;

    const int tid = threadIdx.x;
    const int lx  = tid & (TX - 1);
    const int lyq = tid >> 6;             // 0..3
    const int x   = tx * TX + lx;
    const int y   = ty * TY + lyq;

    const float* dimg = depth + (size_t)b * HW;
    const int base_y = ty * TY - HALO;
    const int base_x = tx * TX - HALO;

    // ---- staging phase A: all global loads to registers (pairs) ----
    float2 stg[NSTG];
#pragma unroll
    for (int i = 0; i < NSTG; ++i) {
        const int t = tid + i * 256;
        const int r = t / SCOLS;
        const int c = t - r * SCOLS;
        const int gy = base_y + r;
        const int gx = base_x + c;
        float a = 0.f, bb2 = 0.f;
        const bool gxok = ((unsigned)gx < (unsigned)WW) && (t < PN);
        if (gxok && (unsigned)gy < (unsigned)HH)       a   = dimg[gy * WW + gx];
        if (gxok && (unsigned)(gy + 1) < (unsigned)HH) bb2 = dimg[(gy + 1) * WW + gx];
        stg[i] = make_float2(a, bb2);
    }

    // ---- streaming plane loads (single-use -> nontemporal) ----
    const int hw = y * WW + x;
    const float* wgt = weight + (size_t)b * (K2 * HW) + hw;
    const float* off = offset + (size_t)b * (2 * K2 * HW) + hw;

    float dyv[K2], dxv[K2], wv[K2];
#pragma unroll
    for (int k = 0; k < K2; ++k) {
        dyv[k] = __builtin_nontemporal_load(&off[(2 * k)     * HW]);
        dxv[k] = __builtin_nontemporal_load(&off[(2 * k + 1) * HW]);
    }
#pragma unroll
    for (int k = 0; k < K2; ++k) wv[k] = __builtin_nontemporal_load(&wgt[k * HW]);

    // ---- staging phase B: LDS writes, then barrier ----
#pragma unroll
    for (int i = 0; i < NSTG; ++i) {
        const int t = tid + i * 256;
        if (t < PN) pd[t] = stg[i];
    }
    __syncthreads();

    // ---- tap phase 1: all addresses + fracs + miss bits (pure VALU) ----
    int   ta[K2];
    float fyv[K2], fxv[K2];
    unsigned miss = 0u;
#pragma unroll
    for (int k = 0; k < K2; ++k) {
        const int kh = k / KK;
        const int kw = k - kh * KK;
        const float py = (float)(y - PAD + kh) + dyv[k];
        const float px = (float)(x - PAD + kw) + dxv[k];
        const float y0f = floorf(py);
        const float x0f = floorf(px);
        fyv[k] = py - y0f;
        fxv[k] = px - x0f;
        const int y0 = (int)y0f;
        const int x0 = (int)x0f;
        const int lr = y0 - base_y;
        const int lc = x0 - base_x;
        const int lrc = min(max(lr, 0), PROWS - 1);
        const int lcc = min(max(lc, 0), SCOLS - 2);
        const bool ok = ((unsigned)lr <= (unsigned)(PROWS - 1)) &
                        ((unsigned)lc <= (unsigned)(SCOLS - 2));
        miss |= ok ? 0u : (1u << k);
        ta[k] = lrc * SCOLS + lcc;
    }

    // ---- tap phase 2: all corner-pair reads, issued back-to-back ----
    float2 c0[K2], c1[K2];
#pragma unroll
    for (int k = 0; k < K2; ++k) {
        c0[k] = pd[ta[k]];          // (v00, v10)
        c1[k] = pd[ta[k] + 1];      // (v01, v11)
    }

    // ---- mean of weights ----
    float wsum = 0.f;
#pragma unroll
    for (int k = 0; k < K2; ++k) wsum += wv[k];
    const float wmean = wsum * (1.0f / 9.0f);

    // ---- tap phase 3: all lerps + FMAs (pure VALU) ----
    float acc = 0.f;
#pragma unroll
    for (int k = 0; k < K2; ++k) {
        const float fy = fyv[k];
        const float fx = fxv[k];
        const float s = (1.f - fy) * ((1.f - fx) * c0[k].x + fx * c1[k].x)
                      + fy         * ((1.f - fx) * c0[k].y + fx * c1[k].y);
        acc = fmaf(wk[k] * (wv[k] - wmean), s, acc);
    }

    // ---- rare exact fixup for taps outside the staged halo ----
    if (miss) {
#pragma unroll 1
        for (int k = 0; k < K2; ++k) {
            if (!(miss & (1u << k))) continue;
            const int kh = k / KK;
            const int kw = k - kh * KK;
            const float dy = off[(2 * k)     * HW];
            const float dx = off[(2 * k + 1) * HW];
            const float wvk = wgt[k * HW];
            const float py = (float)(y - PAD + kh) + dy;
            const float px = (float)(x - PAD + kw) + dx;
            const float y0f = floorf(py);
            const float x0f = floorf(px);
            const float fy = py - y0f;
            const float fx = px - x0f;
            const int y0 = (int)y0f;
            const int x0 = (int)x0f;

            // recompute the (wrong) fast-path sample exactly as above
            const int lrc = min(max(y0 - base_y, 0), PROWS - 1);
            const int lcc = min(max(x0 - base_x, 0), SCOLS - 2);
            const float2 e0 = pd[lrc * SCOLS + lcc];
            const float2 e1 = pd[lrc * SCOLS + lcc + 1];
            const float sf = (1.f - fy) * ((1.f - fx) * e0.x + fx * e1.x)
                           + fy         * ((1.f - fx) * e0.y + fx * e1.y);

            // true sample via global clamped loads + validity-folded weights
            const float wy0 = ((unsigned)y0       < (unsigned)HH) ? (1.f - fy) : 0.f;
            const float wy1 = ((unsigned)(y0 + 1) < (unsigned)HH) ? fy         : 0.f;
            const float wx0 = ((unsigned)x0       < (unsigned)WW) ? (1.f - fx) : 0.f;
            const float wx1 = ((unsigned)(x0 + 1) < (unsigned)WW) ? fx         : 0.f;
            const int y0c = min(max(y0, 0), HH - 1);
            const int y1c = min(max(y0 + 1, 0), HH - 1);
            const int x0c = min(max(x0, 0), WW - 1);
            const int x1c = min(max(x0 + 1, 0), WW - 1);
            const float st = wy0 * (wx0 * dimg[y0c * WW + x0c] + wx1 * dimg[y0c * WW + x1c])
                           + wy1 * (wx0 * dimg[y1c * WW + x0c] + wx1 * dimg[y1c * WW + x1c]);

            acc = fmaf(wk[k] * (wvk - wmean), st - sf, acc);
        }
    }

    // residual from LDS; epilogue (nontemporal store — single-use)
    const float dres = pd[(y - base_y) * SCOLS + (x - base_x)].x;
    __builtin_nontemporal_store(acc + bias[0] + dres, &out[(size_t)b * HW + hw]);
}

extern "C" void kernel_launch(void* const* d_in, const int* in_sizes, int n_in,
                              void* d_out, int out_size, void* d_ws, size_t ws_size,
                              hipStream_t stream) {
    const float* depth  = (const float*)d_in[0];
    const float* weight = (const float*)d_in[1];
    const float* offset = (const float*)d_in[2];
    const float* wk     = (const float*)d_in[3];
    const float* bias   = (const float*)d_in[4];
    float* out = (float*)d_out;

    ppd_kernel<<<NBLK, 256, 0, stream>>>(depth, weight, offset, wk, bias, out);
}

// Round 16
// 20.865 us; speedup vs baseline: 1.5427x; 1.0226x over previous
//
#include <hip/hip_runtime.h>

// Post_process_deconv: out = depth + b + sum_k w[k] * (weight[k] - mean_k(weight)) *
//                           bilinear(depth, y - 1 + kh + dy_k, x - 1 + kw + dx_k)
// Shapes: depth [B,1,H,W], weight [B,9,H,W], offset [B,18,H,W], w [1,1,3,3], b [1]
// B=2, H=352, W=1216, K=3, pad=1. All fp32.
//
// Round 16 = round 15 (row-pair LDS tile, batched taps, XCD-chunked swizzle,
// nontemporal streams) +
//  1. interior fast staging (85% of blocks, block-uniform branch): 6 dwordx2
//     loads + 3 b128 LDS writes per thread (was 12 conditional scalars + 6);
//  2. tap address math + wsum hoisted BEFORE the barrier (depends only on
//     streams, not LDS) -> post-barrier path is just ds_reads + lerps + store.

#define KK 3
#define K2 9
#define PAD 1
#define BB 2
#define HH 352
#define WW 1216

#define TX 64                       // tile width  (19 tiles)
#define TY 4                        // tile height (88 tiles)
#define NTX (WW / TX)
#define NTY (HH / TY)
#define TILES (NTY * NTX)           // 1672
#define NBLK (BB * TILES)           // 3344 = 8 * 418
#define CHUNK (NBLK / 8)            // 418
#define HALO 7
#define SROWS (TY + 2 * HALO + 1)   // 19 raw rows
#define PROWS (SROWS - 1)           // 18 packed row-pair rows
#define SCOLS (TX + 2 * HALO + 2)   // 80
#define PN (PROWS * SCOLS)          // 1440 packed entries
#define NSTG ((PN + 255) / 256)     // 6
#define NPAIR (PN / 2)              // 720 float4 slots

__global__ __launch_bounds__(256, 4) void ppd_kernel(
    const float* __restrict__ depth,   // [B, H*W]
    const float* __restrict__ weight,  // [B, 9, H*W]
    const float* __restrict__ offset,  // [B, 18, H*W]
    const float* __restrict__ wk,      // [9]
    const float* __restrict__ bias,    // [1]
    float* __restrict__ out)           // [B, H*W]
{
    constexpr int HW = HH * WW;

    __shared__ float2 pd[PN];           // 11520 B

    // bijective XCD-chunked swizzle (3344 % 8 == 0)
    const int bid0 = blockIdx.x;
    const int bid  = (bid0 & 7) * CHUNK + (bid0 >> 3);

    const int b   = bid / TILES;
    const int rem = bid - b * TILES;
    const int ty  = rem / NTX;
    const int tx  = rem - ty * NTX;

    const int tid = threadIdx.x;
    const int lx  = tid & (TX - 1);
    const int lyq = tid >> 6;             // 0..3
    const int x   = tx * TX + lx;
    const int y   = ty * TY + lyq;

    const float* dimg = depth + (size_t)b * HW;
    const int base_y = ty * TY - HALO;
    const int base_x = tx * TX - HALO;

    const bool interior = (ty >= 2) & (ty <= 85) & (tx >= 1) & (tx <= 17);

    // ---- staging phase A: global loads to registers ----
    // interior: 6 dwordx2 loads building 3 float4 pair-slots
    // boundary: 12 conditional scalar loads building 6 float2 entries
    float2 fa[3], fb[3];                // interior regs
    float2 stg[NSTG];                   // boundary regs
    if (interior) {
#pragma unroll
        for (int i = 0; i < 3; ++i) {
            const int s = tid + i * 256;        // pair-slot 0..719
            const int e = 2 * s;                // even entry
            const int r = e / SCOLS;
            const int c = e - r * SCOLS;
            const float* p0 = dimg + (base_y + r)     * WW + base_x + c;
            const float* p1 = dimg + (base_y + r + 1) * WW + base_x + c;
            if (s < NPAIR) {
                __builtin_memcpy(&fa[i], p0, 8);
                __builtin_memcpy(&fb[i], p1, 8);
            }
        }
    } else {
#pragma unroll
        for (int i = 0; i < NSTG; ++i) {
            const int t = tid + i * 256;
            const int r = t / SCOLS;
            const int c = t - r * SCOLS;
            const int gy = base_y + r;
            const int gx = base_x + c;
            float a = 0.f, bb2 = 0.f;
            const bool gxok = ((unsigned)gx < (unsigned)WW) && (t < PN);
            if (gxok && (unsigned)gy < (unsigned)HH)       a   = dimg[gy * WW + gx];
            if (gxok && (unsigned)(gy + 1) < (unsigned)HH) bb2 = dimg[(gy + 1) * WW + gx];
            stg[i] = make_float2(a, bb2);
        }
    }

    // ---- streaming plane loads (single-use -> nontemporal) ----
    const int hw = y * WW + x;
    const float* wgt = weight + (size_t)b * (K2 * HW) + hw;
    const float* off = offset + (size_t)b * (2 * K2 * HW) + hw;

    float dyv[K2], dxv[K2], wv[K2];
#pragma unroll
    for (int k = 0; k < K2; ++k) {
        dyv[k] = __builtin_nontemporal_load(&off[(2 * k)     * HW]);
        dxv[k] = __builtin_nontemporal_load(&off[(2 * k + 1) * HW]);
    }
#pragma unroll
    for (int k = 0; k < K2; ++k) wv[k] = __builtin_nontemporal_load(&wgt[k * HW]);

    // ---- staging phase B: LDS writes (waits staging loads only) ----
    if (interior) {
#pragma unroll
        for (int i = 0; i < 3; ++i) {
            const int s = tid + i * 256;
            if (s < NPAIR) {
                float4 q = make_float4(fa[i].x, fb[i].x, fa[i].y, fb[i].y);
                *reinterpret_cast<float4*>(&pd[2 * s]) = q;
            }
        }
    } else {
#pragma unroll
        for (int i = 0; i < NSTG; ++i) {
            const int t = tid + i * 256;
            if (t < PN) pd[t] = stg[i];
        }
    }

    // ---- PRE-BARRIER: tap addresses + fracs + miss bits + wsum ----
    int   ta[K2];
    float fyv[K2], fxv[K2];
    unsigned miss = 0u;
#pragma unroll
    for (int k = 0; k < K2; ++k) {
        const int kh = k / KK;
        const int kw = k - kh * KK;
        const float py = (float)(y - PAD + kh) + dyv[k];
        const float px = (float)(x - PAD + kw) + dxv[k];
        const float y0f = floorf(py);
        const float x0f = floorf(px);
        fyv[k] = py - y0f;
        fxv[k] = px - x0f;
        const int y0 = (int)y0f;
        const int x0 = (int)x0f;
        const int lr = y0 - base_y;
        const int lc = x0 - base_x;
        const int lrc = min(max(lr, 0), PROWS - 1);
        const int lcc = min(max(lc, 0), SCOLS - 2);
        const bool ok = ((unsigned)lr <= (unsigned)(PROWS - 1)) &
                        ((unsigned)lc <= (unsigned)(SCOLS - 2));
        miss |= ok ? 0u : (1u << k);
        ta[k] = lrc * SCOLS + lcc;
    }

    float wsum = 0.f;
#pragma unroll
    for (int k = 0; k < K2; ++k) wsum += wv[k];
    const float wmean = wsum * (1.0f / 9.0f);

    __syncthreads();

    // ---- POST-BARRIER: all corner-pair reads back-to-back, then lerps ----
    float2 c0[K2], c1[K2];
#pragma unroll
    for (int k = 0; k < K2; ++k) {
        c0[k] = pd[ta[k]];          // (v00, v10)
        c1[k] = pd[ta[k] + 1];      // (v01, v11)
    }

    float acc = 0.f;
#pragma unroll
    for (int k = 0; k < K2; ++k) {
        const float fy = fyv[k];
        const float fx = fxv[k];
        const float s = (1.f - fy) * ((1.f - fx) * c0[k].x + fx * c1[k].x)
                      + fy         * ((1.f - fx) * c0[k].y + fx * c1[k].y);
        acc = fmaf(wk[k] * (wv[k] - wmean), s, acc);
    }

    // ---- rare exact fixup for taps outside the staged halo ----
    if (miss) {
#pragma unroll 1
        for (int k = 0; k < K2; ++k) {
            if (!(miss & (1u << k))) continue;
            const int kh = k / KK;
            const int kw = k - kh * KK;
            const float dy = off[(2 * k)     * HW];
            const float dx = off[(2 * k + 1) * HW];
            const float wvk = wgt[k * HW];
            const float py = (float)(y - PAD + kh) + dy;
            const float px = (float)(x - PAD + kw) + dx;
            const float y0f = floorf(py);
            const float x0f = floorf(px);
            const float fy = py - y0f;
            const float fx = px - x0f;
            const int y0 = (int)y0f;
            const int x0 = (int)x0f;

            // recompute the (wrong) fast-path sample exactly as above
            const int lrc = min(max(y0 - base_y, 0), PROWS - 1);
            const int lcc = min(max(x0 - base_x, 0), SCOLS - 2);
            const float2 e0 = pd[lrc * SCOLS + lcc];
            const float2 e1 = pd[lrc * SCOLS + lcc + 1];
            const float sf = (1.f - fy) * ((1.f - fx) * e0.x + fx * e1.x)
                           + fy         * ((1.f - fx) * e0.y + fx * e1.y);

            // true sample via global clamped loads + validity-folded weights
            const float wy0 = ((unsigned)y0       < (unsigned)HH) ? (1.f - fy) : 0.f;
            const float wy1 = ((unsigned)(y0 + 1) < (unsigned)HH) ? fy         : 0.f;
            const float wx0 = ((unsigned)x0       < (unsigned)WW) ? (1.f - fx) : 0.f;
            const float wx1 = ((unsigned)(x0 + 1) < (unsigned)WW) ? fx         : 0.f;
            const int y0c = min(max(y0, 0), HH - 1);
            const int y1c = min(max(y0 + 1, 0), HH - 1);
            const int x0c = min(max(x0, 0), WW - 1);
            const int x1c = min(max(x0 + 1, 0), WW - 1);
            const float st = wy0 * (wx0 * dimg[y0c * WW + x0c] + wx1 * dimg[y0c * WW + x1c])
                           + wy1 * (wx0 * dimg[y1c * WW + x0c] + wx1 * dimg[y1c * WW + x1c]);

            acc = fmaf(wk[k] * (wvk - wmean), st - sf, acc);
        }
    }

    // residual from LDS; epilogue (nontemporal store — single-use)
    const float dres = pd[(y - base_y) * SCOLS + (x - base_x)].x;
    __builtin_nontemporal_store(acc + bias[0] + dres, &out[(size_t)b * HW + hw]);
}

extern "C" void kernel_launch(void* const* d_in, const int* in_sizes, int n_in,
                              void* d_out, int out_size, void* d_ws, size_t ws_size,
                              hipStream_t stream) {
    const float* depth  = (const float*)d_in[0];
    const float* weight = (const float*)d_in[1];
    const float* offset = (const float*)d_in[2];
    const float* wk     = (const float*)d_in[3];
    const float* bias   = (const float*)d_in[4];
    float* out = (float*)d_out;

    ppd_kernel<<<NBLK, 256, 0, stream>>>(depth, weight, offset, wk, bias, out);
}